// Round 7
// baseline (484.983 us; speedup 1.0000x reference)
//
#include <hip/hip_runtime.h>

// TAdaConv2d via bf16 MFMA implicit GEMM — persistent blocks, 16 waves/CU, 6-slot ring.
//   out[b,co,t,y,w] = bias[co] + sum_{ci,ky,kx} x[b,ci,t,y+ky-1,w+kx-1]*alpha[b,ci,t]*W[co,ci,ky,kx]
//
// R7 = second resubmit. R5: container acquisition failed. R6: `HIP error 100: no
// ROCm-capable device` at hipMalloc during INPUT UPLOAD — before any kernel of ours
// ran. Both are infra failures; kernel never executed. Static audit clean (no OOB,
// no barrier divergence, ring slot sets disjoint). Rationale unchanged:
// R1-R4 all latency-bound at ~15-25% on every pipe. conv6 had only 8 waves/CU (LDS
// 67.5KB -> 2 blocks); conv4 had 16 waves/CU but 2x LDS traffic. conv7 combines:
//   - 512-thread blocks, 8 waves = (ns px-half, mg co-half, rw row). 36 ds_read + 72 MFMA
//     per wave per step; B-frag feeds both co-quarters (0.5KB LDS/MFMA).
//   - ring 6 slots (50.7KB); acc 16 + fb 16 regs -> VGPR <= 128 under
//     __launch_bounds__(512,4) => 2 blocks/CU = 16 waves/CU = 4 waves/SIMD.
//   - step order: loads -> MFMA -> convert+ds_write -> barrier -> stores.
// Accumulation order (tap,kc) unchanged -> bit-identical, absmax 0.0156.

#define CIN  64
#define COUT 64
#define TT   16
#define BB   8
#define HH   64
#define WW   64
#define NSTEP 8

typedef __attribute__((ext_vector_type(8))) short bf16x8;
typedef __attribute__((ext_vector_type(4))) float f32x4;

__device__ __forceinline__ unsigned short f2bf(float f) {
    // round-to-nearest-even fp32 -> bf16
    union { float f; unsigned u; } v; v.f = f;
    unsigned r = (v.u + 0x7FFF + ((v.u >> 16) & 1)) >> 16;
    return (unsigned short)r;
}

// ---------------- prep_w: weight -> wb[q][tap][kc][kg][co_l][8] bf16 ----------------
__global__ __launch_bounds__(256) void prep_w(const float* __restrict__ wgt,
                                              unsigned short* __restrict__ wb) {
    int idx = blockIdx.x * 256 + threadIdx.x;   // over co*ci*tap = 36864
    if (idx < COUT * CIN * 9) {
        int co  = idx / (CIN * 9);
        int r   = idx - co * (CIN * 9);
        int ci  = r / 9;
        int tap = r - ci * 9;
        int q    = co >> 4;
        int co_l = co & 15;
        int kc   = ci >> 5;
        int kg   = (ci >> 3) & 3;
        int e    = ci & 7;
        wb[(((((q * 9 + tap) * 2 + kc) * 4 + kg) * 16) + co_l) * 8 + e] = f2bf(wgt[idx]);
    }
}

// ---------------- conv7: persistent 8-wave rolling-ring MFMA implicit GEMM ----------------
// block: (bt, y-quarter): 16 output rows x 64 w, all 64 co; 8 steps of 2 rows.
// 8 waves = (ns px-half) x (mg co-half) x (rw row). xs = 6-slot ring of input rows.
__global__ __launch_bounds__(512, 4) void conv7(const float* __restrict__ x,
                                                const float* __restrict__ alpha,
                                                const short* __restrict__ wb,
                                                const float* __restrict__ bias,
                                                float* __restrict__ out) {
    __shared__ __align__(16) short xs[6 * 4224];   // 6 row slots x (66 px x 64 ci), 50.7 KB

    // XCD swizzle: 512 blocks = 8 XCDs x 64; all 4 quarters of a (b,t) on one XCD.
    const int orig = blockIdx.x;
    const int blk  = (orig & 7) * 64 + (orig >> 3);
    const int qy   = blk & 3;
    const int bt   = blk >> 2;
    const int t    = bt & 15;
    const int b    = bt >> 4;
    const int yb   = qy * 16;
    const int tid  = threadIdx.x;
    const int wv   = tid >> 6;           // 0..7; also ci-group during staging
    const int lane = tid & 63;
    const int co_l = lane & 15;
    const int kg   = lane >> 4;
    const int rw   = wv & 1;             // output row within step
    const int mg   = (wv >> 1) & 1;      // co half (quarters 2mg, 2mg+1) in registers
    const int ns   = wv >> 2;            // pixel half (cols ns*32 .. ns*32+31)

    // ---- weight fragments -> 72 VGPRs ----
    bf16x8 wreg[2][9][2];
#pragma unroll
    for (int m = 0; m < 2; ++m)
#pragma unroll
        for (int tap = 0; tap < 9; ++tap)
#pragma unroll
            for (int kc = 0; kc < 2; ++kc)
                wreg[m][tap][kc] = *(const bf16x8*)(
                    wb + ((((mg * 2 + m) * 9 + tap) * 2 + kc) * 64 + lane) * 8);

    // ---- alpha for this wave's ci-group wv (wave-uniform -> SGPR) ----
    float av[8];
#pragma unroll
    for (int j = 0; j < 8; ++j) {
        float a = alpha[(b * CIN + wv * 8 + j) * TT + t];
        av[j] = __builtin_bit_cast(
            float, __builtin_amdgcn_readfirstlane(__builtin_bit_cast(int, a)));
    }

    const float* xb = x + (size_t)((b * CIN + wv * 8) * TT + t) * (HH * WW);

    // ---- halo columns px=0, px=65 of all 6 slots: zero once ----
    if (tid < 96) {
        int slot = tid >> 4, col = (tid >> 3) & 1, sg = tid & 7;
        int4 z = {0, 0, 0, 0};
        *(int4*)(xs + slot * 4224 + col * 4160 + sg * 8) = z;
    }

    // ---- staging helpers: wave wv stages ci-group wv of one row ----
    auto stage_load = [&](int gy, float* f) {
        const bool ok = (unsigned)gy < HH;
        const float* p = xb + gy * WW + lane;     // 64 lanes -> 256B coalesced
#pragma unroll
        for (int j = 0; j < 8; ++j) f[j] = ok ? p[j * 65536] : 0.0f;
    };
    auto stage_store = [&](int slot, const float* f) {
        int4 o;
        o.x = (int)f2bf(f[0] * av[0]) | ((int)f2bf(f[1] * av[1]) << 16);
        o.y = (int)f2bf(f[2] * av[2]) | ((int)f2bf(f[3] * av[3]) << 16);
        o.z = (int)f2bf(f[4] * av[4]) | ((int)f2bf(f[5] * av[5]) << 16);
        o.w = (int)f2bf(f[6] * av[6]) | ((int)f2bf(f[7] * av[7]) << 16);
        *(int4*)(xs + slot * 4224 + (lane + 1) * 64 + ((wv ^ (lane & 7)) * 8)) = o;
    };

    // ---- prologue: rows yb-1..yb+2 -> slots 0..3 ----
    {
        float fp[4][8];
#pragma unroll
        for (int r = 0; r < 4; ++r) stage_load(yb - 1 + r, fp[r]);
#pragma unroll
        for (int r = 0; r < 4; ++r) stage_store(r, fp[r]);
    }

    // per-(dx,kc) ds base; pixel sub-tile nl folds into +nl*1024 offset imm
    int si[3][2];
#pragma unroll
    for (int dxi = 0; dxi < 3; ++dxi)
#pragma unroll
        for (int kc = 0; kc < 2; ++kc) {
            int wx = ns * 32 + co_l + dxi - 1;             // -1..47
            si[dxi][kc] = (wx + 1) * 64 + (((kc * 4 + kg) ^ (wx & 7)) * 8);
        }

    __syncthreads();

    // ---- 8-step pipelined main loop (fully unrolled: ring slots compile-time) ----
    float fb[2][8];
#pragma unroll
    for (int it = 0; it < NSTEP; ++it) {
        const int s0 = (2 * it) % 6;                       // slot of input row yb+2it-1

        // (a) issue next-2-rows loads; latency hides under MFMA
        if (it < NSTEP - 1) {
            stage_load(yb + 2 * it + 3, fb[0]);
            stage_load(yb + 2 * it + 4, fb[1]);
        }

        // (b) compute this step's 2 output rows (this wave: 32 co x 1 row x 32 px)
        f32x4 acc[2][2] = {};
#pragma unroll
        for (int tap = 0; tap < 9; ++tap) {
            const int ky  = tap / 3;
            const int dxi = tap - 3 * ky;
            int u = s0 + rw + ky; if (u >= 6) u -= 6;      // rw runtime, rest const
            const short* rowp = xs + u * 4224;
#pragma unroll
            for (int kc = 0; kc < 2; ++kc) {
                const short* bp = rowp + si[dxi][kc];
#pragma unroll
                for (int nl = 0; nl < 2; ++nl) {
                    bf16x8 bfr = *(const bf16x8*)(bp + nl * 1024);   // offset imm
                    acc[0][nl] = __builtin_amdgcn_mfma_f32_16x16x32_bf16(
                        wreg[0][tap][kc], bfr, acc[0][nl], 0, 0, 0);
                    acc[1][nl] = __builtin_amdgcn_mfma_f32_16x16x32_bf16(
                        wreg[1][tap][kc], bfr, acc[1][nl], 0, 0, 0);
                }
            }
        }

        // (c) convert + ring write (vmcnt wait for (a) lands here)
        if (it < NSTEP - 1) {
            stage_store((2 * it + 4) % 6, fb[0]);
            stage_store((2 * it + 5) % 6, fb[1]);
        }

        // (d) barrier, then (e) stores drain under next step's work
        if (it < NSTEP - 1) __syncthreads();

        const int y = yb + 2 * it + rw;
#pragma unroll
        for (int m = 0; m < 2; ++m)
#pragma unroll
            for (int rr = 0; rr < 4; ++rr) {
                const int co = (mg * 2 + m) * 16 + kg * 4 + rr;
                const float bv = bias[co];
                float* op = out + (size_t)(((b * COUT + co) * TT + t) * HH + y) * WW;
#pragma unroll
                for (int nl = 0; nl < 2; ++nl)
                    op[ns * 32 + nl * 16 + co_l] = acc[m][nl][rr] + bv;
            }
    }
}

extern "C" void kernel_launch(void* const* d_in, const int* in_sizes, int n_in,
                              void* d_out, int out_size, void* d_ws, size_t ws_size,
                              hipStream_t stream) {
    const float* x      = (const float*)d_in[0];
    const float* alpha  = (const float*)d_in[1];
    const float* weight = (const float*)d_in[2];
    const float* bias   = (const float*)d_in[3];
    float* out          = (float*)d_out;

    // workspace: wb only (73.7 KB)
    unsigned short* wb = (unsigned short*)d_ws;

    hipLaunchKernelGGL(prep_w, dim3(144), dim3(256), 0, stream, weight, wb);
    hipLaunchKernelGGL(conv7, dim3(8 * 64), dim3(512), 0, stream,
                       x, alpha, (const short*)wb, bias, out);
}

// Round 8
// 293.049 us; speedup vs baseline: 1.6550x; 1.6550x over previous
//
#include <hip/hip_runtime.h>

// TAdaConv2d via bf16 MFMA implicit GEMM — persistent blocks, DRAM-efficiency pass.
//   out[b,co,t,y,w] = bias[co] + sum_{ci,ky,kx} x[b,ci,t,y+ky-1,w+kx-1]*alpha[b,ci,t]*W[co,ci,ky,kx]
//
// R8 vs R7: conv7 SPILLED (wreg = 36 bf16x8 = 144 VGPR, not 72; cap 128 -> scratch,
// FETCH 584MB, 336us). Reverting to conv6's proven reg structure (W144+A32+F32 ~ 210
// regs @ 256-cap, 2 blocks x 4 waves/CU) and attacking the OTHER anomaly: all of
// conv3..conv6 ran at 2.0+-0.2 TB/s effective HBM while fillBuffer does 6.8 TB/s.
//   1. dwordx2 row-PAIR staging loads (rows contiguous in x): 512B/instr granule,
//      half the load instructions. lane = (rowhalf, px-pair).
//   2. __builtin_nontemporal_store for out: stop evicting x from L3 every iteration
//      (FETCH was 72MB ~ half of x re-fetched per pass). Key counter: FETCH -> <25MB.
//   3. ring 8 -> 6 slots (conv6 over-allocated; conv7's verified 6-slot indexing).
// Accumulation order (tap,kc) unchanged -> bit-identical, absmax 0.0156.

#define CIN  64
#define COUT 64
#define TT   16
#define BB   8
#define HH   64
#define WW   64
#define NSTEP 8

typedef __attribute__((ext_vector_type(8))) short bf16x8;
typedef __attribute__((ext_vector_type(4))) float f32x4;

__device__ __forceinline__ unsigned short f2bf(float f) {
    // round-to-nearest-even fp32 -> bf16
    union { float f; unsigned u; } v; v.f = f;
    unsigned r = (v.u + 0x7FFF + ((v.u >> 16) & 1)) >> 16;
    return (unsigned short)r;
}

// ---------------- prep_w: weight -> wb[q][tap][kc][kg][co_l][8] bf16 ----------------
__global__ __launch_bounds__(256) void prep_w(const float* __restrict__ wgt,
                                              unsigned short* __restrict__ wb) {
    int idx = blockIdx.x * 256 + threadIdx.x;   // over co*ci*tap = 36864
    if (idx < COUT * CIN * 9) {
        int co  = idx / (CIN * 9);
        int r   = idx - co * (CIN * 9);
        int ci  = r / 9;
        int tap = r - ci * 9;
        int q    = co >> 4;
        int co_l = co & 15;
        int kc   = ci >> 5;
        int kg   = (ci >> 3) & 3;
        int e    = ci & 7;
        wb[(((((q * 9 + tap) * 2 + kc) * 4 + kg) * 16) + co_l) * 8 + e] = f2bf(wgt[idx]);
    }
}

// ---------------- conv8: persistent-block rolling-ring MFMA implicit GEMM ----------------
// block: (bt, y-quarter): 16 output rows x 64 w, all 64 co; 8 steps of 2 rows.
// 4 waves = (mg co-half) x (rw row). xs = 6-slot ring of input rows.
__global__ __launch_bounds__(256, 2) void conv8(const float* __restrict__ x,
                                                const float* __restrict__ alpha,
                                                const short* __restrict__ wb,
                                                const float* __restrict__ bias,
                                                float* __restrict__ out) {
    __shared__ __align__(16) short xs[6 * 4224];   // 6 row slots x (66 px x 64 ci), 50.7 KB

    // XCD swizzle: 512 blocks = 8 XCDs x 64; all 4 quarters of a (b,t) on one XCD.
    const int orig = blockIdx.x;
    const int blk  = (orig & 7) * 64 + (orig >> 3);
    const int qy   = blk & 3;
    const int bt   = blk >> 2;
    const int t    = bt & 15;
    const int b    = bt >> 4;
    const int yb   = qy * 16;
    const int tid  = threadIdx.x;
    const int wv   = tid >> 6;
    const int lane = tid & 63;
    const int co_l = lane & 15;
    const int kg   = lane >> 4;
    const int mg   = wv >> 1;            // co half (quarters 2mg, 2mg+1) in registers
    const int rw   = wv & 1;             // output row within step
    const int rh   = lane >> 5;          // row-half for pair staging
    const int pp   = (lane & 31) * 2;    // px pair base for staging

    // ---- weight fragments -> 144 VGPRs (known-good at 256-reg cap, conv5/6) ----
    bf16x8 wreg[2][9][2];
#pragma unroll
    for (int m = 0; m < 2; ++m)
#pragma unroll
        for (int tap = 0; tap < 9; ++tap)
#pragma unroll
            for (int kc = 0; kc < 2; ++kc)
                wreg[m][tap][kc] = *(const bf16x8*)(
                    wb + ((((mg * 2 + m) * 9 + tap) * 2 + kc) * 64 + lane) * 8);

    // ---- alpha for this wave's two ci-groups (wave-uniform -> SGPR) ----
    float av[2][8];
#pragma unroll
    for (int gi = 0; gi < 2; ++gi)
#pragma unroll
        for (int j = 0; j < 8; ++j) {
            float a = alpha[(b * CIN + (wv + gi * 4) * 8 + j) * TT + t];
            av[gi][j] = __builtin_bit_cast(
                float, __builtin_amdgcn_readfirstlane(__builtin_bit_cast(int, a)));
        }

    // wave wv owns ci-groups {wv, wv+4}; float2 view: element `lane` spans 2 rows x 32 px-pairs
    const float* xb0 = x + (size_t)((b * CIN + wv * 8) * TT + t) * (HH * WW);
    const float* xb1 = x + (size_t)((b * CIN + (wv + 4) * 8) * TT + t) * (HH * WW);

    // ---- halo columns px=0, px=65 of all 6 slots: zero once ----
    if (tid < 96) {
        int slot = tid >> 4, col = (tid >> 3) & 1, sg = tid & 7;
        int4 z = {0, 0, 0, 0};
        *(int4*)(xs + slot * 4224 + col * 4160 + sg * 8) = z;
    }

    // ---- staging: row-PAIR loads (dwordx2; rows gy0, gy0+1 contiguous in memory) ----
    float2 fb[2][8];                      // [gi][ci] ; each lane: row gy0+rh, px pp..pp+1
    auto stage_load = [&](int gy0) {
        const int gy = gy0 + rh;
        const bool ok = (unsigned)gy < HH;
        const float2* p0 = (const float2*)(xb0 + (size_t)gy0 * WW) + lane;
        const float2* p1 = (const float2*)(xb1 + (size_t)gy0 * WW) + lane;
        const float2 z = {0.0f, 0.0f};
#pragma unroll
        for (int j = 0; j < 8; ++j) {
            fb[0][j] = ok ? p0[j * 32768] : z;
            fb[1][j] = ok ? p1[j * 32768] : z;
        }
    };
    // store pair batch: slots (sA for row gy0, sB for row gy0+1)
    auto stage_store = [&](int sA, int sB) {
        const int sl = rh ? sB : sA;
#pragma unroll
        for (int gi = 0; gi < 2; ++gi) {
            const int g = wv + gi * 4;
            int4 e, o;
            e.x = (int)f2bf(fb[gi][0].x * av[gi][0]) | ((int)f2bf(fb[gi][1].x * av[gi][1]) << 16);
            e.y = (int)f2bf(fb[gi][2].x * av[gi][2]) | ((int)f2bf(fb[gi][3].x * av[gi][3]) << 16);
            e.z = (int)f2bf(fb[gi][4].x * av[gi][4]) | ((int)f2bf(fb[gi][5].x * av[gi][5]) << 16);
            e.w = (int)f2bf(fb[gi][6].x * av[gi][6]) | ((int)f2bf(fb[gi][7].x * av[gi][7]) << 16);
            o.x = (int)f2bf(fb[gi][0].y * av[gi][0]) | ((int)f2bf(fb[gi][1].y * av[gi][1]) << 16);
            o.y = (int)f2bf(fb[gi][2].y * av[gi][2]) | ((int)f2bf(fb[gi][3].y * av[gi][3]) << 16);
            o.z = (int)f2bf(fb[gi][4].y * av[gi][4]) | ((int)f2bf(fb[gi][5].y * av[gi][5]) << 16);
            o.w = (int)f2bf(fb[gi][6].y * av[gi][6]) | ((int)f2bf(fb[gi][7].y * av[gi][7]) << 16);
            *(int4*)(xs + sl * 4224 + (pp + 1) * 64 + ((g ^ (pp & 7)) * 8))       = e;
            *(int4*)(xs + sl * 4224 + (pp + 2) * 64 + ((g ^ ((pp + 1) & 7)) * 8)) = o;
        }
    };

    // ---- prologue: rows yb-1..yb+2 -> slots 0..3 (two pair batches) ----
    stage_load(yb - 1); stage_store(0, 1);
    stage_load(yb + 1); stage_store(2, 3);

    // per-(dx,kc) ds base; pixel-tile n folds into +n*1024 offset imm
    int si[3][2];
#pragma unroll
    for (int dxi = 0; dxi < 3; ++dxi)
#pragma unroll
        for (int kc = 0; kc < 2; ++kc) {
            int wx = co_l + dxi - 1;                       // -1..15
            si[dxi][kc] = (wx + 1) * 64 + (((kc * 4 + kg) ^ (wx & 7)) * 8);
        }

    __syncthreads();

    // ---- 8-step pipelined main loop (fully unrolled: ring slots compile-time) ----
#pragma unroll
    for (int it = 0; it < NSTEP; ++it) {
        const int s0 = (2 * it) % 6;                       // slot of input row yb+2it-1

        // (a) issue next-pair loads; latency hides under MFMA
        if (it < NSTEP - 1) stage_load(yb + 2 * it + 3);

        // (b) compute this step's 2 output rows (this wave: 32 co x 1 row x 64 px)
        f32x4 acc[2][4] = {};
#pragma unroll
        for (int tap = 0; tap < 9; ++tap) {
            const int ky  = tap / 3;
            const int dxi = tap - 3 * ky;
            int u = s0 + rw + ky; if (u >= 6) u -= 6;      // rw runtime, rest const
            const short* rowp = xs + u * 4224;
#pragma unroll
            for (int kc = 0; kc < 2; ++kc) {
                const short* bp = rowp + si[dxi][kc];
#pragma unroll
                for (int n = 0; n < 4; ++n) {
                    bf16x8 bfr = *(const bf16x8*)(bp + n * 1024);   // offset imm
                    acc[0][n] = __builtin_amdgcn_mfma_f32_16x16x32_bf16(
                        wreg[0][tap][kc], bfr, acc[0][n], 0, 0, 0);
                    acc[1][n] = __builtin_amdgcn_mfma_f32_16x16x32_bf16(
                        wreg[1][tap][kc], bfr, acc[1][n], 0, 0, 0);
                }
            }
        }

        // (c) convert + ring write (vmcnt wait for (a) lands here)
        if (it < NSTEP - 1) stage_store((2 * it + 4) % 6, (2 * it + 5) % 6);

        // (d) barrier, then (e) nt-stores drain under next step's work
        if (it < NSTEP - 1) __syncthreads();

        const int y = yb + 2 * it + rw;
#pragma unroll
        for (int m = 0; m < 2; ++m)
#pragma unroll
            for (int rr = 0; rr < 4; ++rr) {
                const int co = (mg * 2 + m) * 16 + kg * 4 + rr;
                const float bv = bias[co];
                float* op = out + (size_t)(((b * COUT + co) * TT + t) * HH + y) * WW;
#pragma unroll
                for (int n = 0; n < 4; ++n)
                    __builtin_nontemporal_store(acc[m][n][rr] + bv, &op[n * 16 + co_l]);
            }
    }
}

extern "C" void kernel_launch(void* const* d_in, const int* in_sizes, int n_in,
                              void* d_out, int out_size, void* d_ws, size_t ws_size,
                              hipStream_t stream) {
    const float* x      = (const float*)d_in[0];
    const float* alpha  = (const float*)d_in[1];
    const float* weight = (const float*)d_in[2];
    const float* bias   = (const float*)d_in[3];
    float* out          = (float*)d_out;

    // workspace: wb only (73.7 KB)
    unsigned short* wb = (unsigned short*)d_ws;

    hipLaunchKernelGGL(prep_w, dim3(144), dim3(256), 0, stream, weight, wb);
    hipLaunchKernelGGL(conv8, dim3(8 * 64), dim3(256), 0, stream,
                       x, alpha, (const short*)wb, bias, out);
}

// Round 9
// 280.515 us; speedup vs baseline: 1.7289x; 1.0447x over previous
//
#include <hip/hip_runtime.h>

// TAdaConv2d via bf16 MFMA implicit GEMM — conv6 + nontemporal stores (single-variable probe).
//   out[b,co,t,y,w] = bias[co] + sum_{ci,ky,kx} x[b,ci,t,y+ky-1,w+kx-1]*alpha[b,ci,t]*W[co,ci,ky,kx]
//
// R9 vs R8: conv8 conflated 3 changes and regressed (nt + pair-loads + 6-slot ring;
// WRITE 131->192MB, FETCH 72->98MB, +590K write conflicts from pp-parity swizzle bug).
// Unified theory from R0-R8: all four schedule variants sit at 2.0-2.1 TB/s effective —
// an ACCESS-GRANULARITY roofline (256B strided reads + 4x64B scattered writes), not a
// latency/schedule problem. FETCH 72MB < x's 134MB => x partially L3-resident; the out
// write stream (131MB/iter through L3) evicts the rest.
// conv9 = conv6 VERBATIM (101us, no spill, 0 conflicts) + __builtin_nontemporal_store
// on the epilogue only. Pre-committed readings:
//   FETCH<30 & WRITE~131 & dur~85  -> writes evict x; next: LDS-transpose epilogue.
//   FETCH dn & WRITE>160 & dur flat -> nt amplifies 64B writes; next: transpose + regular.
//   FETCH unchanged                 -> theory wrong; stop structural work.

#define CIN  64
#define COUT 64
#define TT   16
#define BB   8
#define HH   64
#define WW   64
#define NSTEP 8

typedef __attribute__((ext_vector_type(8))) short bf16x8;
typedef __attribute__((ext_vector_type(4))) float f32x4;

__device__ __forceinline__ unsigned short f2bf(float f) {
    // round-to-nearest-even fp32 -> bf16
    union { float f; unsigned u; } v; v.f = f;
    unsigned r = (v.u + 0x7FFF + ((v.u >> 16) & 1)) >> 16;
    return (unsigned short)r;
}

// ---------------- prep_w: weight -> wb[q][tap][kc][kg][co_l][8] bf16 ----------------
__global__ __launch_bounds__(256) void prep_w(const float* __restrict__ wgt,
                                              unsigned short* __restrict__ wb) {
    int idx = blockIdx.x * 256 + threadIdx.x;   // over co*ci*tap = 36864
    if (idx < COUT * CIN * 9) {
        int co  = idx / (CIN * 9);
        int r   = idx - co * (CIN * 9);
        int ci  = r / 9;
        int tap = r - ci * 9;
        int q    = co >> 4;
        int co_l = co & 15;
        int kc   = ci >> 5;
        int kg   = (ci >> 3) & 3;
        int e    = ci & 7;
        wb[(((((q * 9 + tap) * 2 + kc) * 4 + kg) * 16) + co_l) * 8 + e] = f2bf(wgt[idx]);
    }
}

// ---------------- conv9: persistent-block rolling-ring MFMA implicit GEMM ----------------
// block: (bt, y-quarter): 16 output rows x 64 w, all 64 co; 8 steps of 2 rows.
// 4 waves = (mg co-half) x (rw row). xs = 8-slot ring of input rows.
__global__ __launch_bounds__(256, 2) void conv9(const float* __restrict__ x,
                                                const float* __restrict__ alpha,
                                                const short* __restrict__ wb,
                                                const float* __restrict__ bias,
                                                float* __restrict__ out) {
    __shared__ __align__(16) short xs[8 * 4224];   // 8 row slots x (66 px x 64 ci), 66 KB

    // XCD swizzle: 512 blocks = 8 XCDs x 64; all 4 quarters of a (b,t) on one XCD.
    const int orig = blockIdx.x;
    const int blk  = (orig & 7) * 64 + (orig >> 3);
    const int qy   = blk & 3;
    const int bt   = blk >> 2;
    const int t    = bt & 15;
    const int b    = bt >> 4;
    const int yb   = qy * 16;
    const int tid  = threadIdx.x;
    const int wv   = tid >> 6;
    const int lane = tid & 63;
    const int co_l = lane & 15;
    const int kg   = lane >> 4;
    const int mg   = wv >> 1;            // co half (quarters 2mg, 2mg+1) in registers
    const int rw   = wv & 1;             // output row within step

    // ---- weight fragments -> 144 VGPRs ----
    bf16x8 wreg[2][9][2];
#pragma unroll
    for (int m = 0; m < 2; ++m)
#pragma unroll
        for (int tap = 0; tap < 9; ++tap)
#pragma unroll
            for (int kc = 0; kc < 2; ++kc)
                wreg[m][tap][kc] = *(const bf16x8*)(
                    wb + ((((mg * 2 + m) * 9 + tap) * 2 + kc) * 64 + lane) * 8);

    // ---- alpha for this wave's two ci-groups (wave-uniform -> SGPR) ----
    float av[2][8];
#pragma unroll
    for (int gi = 0; gi < 2; ++gi)
#pragma unroll
        for (int j = 0; j < 8; ++j) {
            float a = alpha[(b * CIN + (wv + gi * 4) * 8 + j) * TT + t];
            av[gi][j] = __builtin_bit_cast(
                float, __builtin_amdgcn_readfirstlane(__builtin_bit_cast(int, a)));
        }

    const float* xbase0 = x + (size_t)((b * CIN + wv * 8) * TT + t) * (HH * WW);
    const float* xbase1 = x + (size_t)((b * CIN + (wv + 4) * 8) * TT + t) * (HH * WW);

    // ---- halo columns px=0, px=65 of all 8 slots: zero once ----
    if (tid < 128) {
        int slot = tid >> 4, col = (tid >> 3) & 1, sg = tid & 7;
        int4 z = {0, 0, 0, 0};
        *(int4*)(xs + slot * 4224 + col * 4160 + sg * 8) = z;
    }

    // ---- staging helpers (wave wv owns ci-groups {wv, wv+4} for both rows of a batch) ----
    float fb[2][2][8];                    // [row][gi][j] in-flight registers
    auto stage_load = [&](int gy0) {
#pragma unroll
        for (int r = 0; r < 2; ++r) {
            const int gy = gy0 + r;
            const bool ok = (unsigned)gy < HH;
            const float* p0 = xbase0 + gy * WW + lane;
            const float* p1 = xbase1 + gy * WW + lane;
#pragma unroll
            for (int j = 0; j < 8; ++j) {
                fb[r][0][j] = ok ? p0[j * 65536] : 0.0f;
                fb[r][1][j] = ok ? p1[j * 65536] : 0.0f;
            }
        }
    };
    auto stage_store = [&](int s0) {
#pragma unroll
        for (int r = 0; r < 2; ++r)
#pragma unroll
            for (int gi = 0; gi < 2; ++gi) {
                const int g = wv + gi * 4;
                int4 o;
                o.x = (int)f2bf(fb[r][gi][0] * av[gi][0]) | ((int)f2bf(fb[r][gi][1] * av[gi][1]) << 16);
                o.y = (int)f2bf(fb[r][gi][2] * av[gi][2]) | ((int)f2bf(fb[r][gi][3] * av[gi][3]) << 16);
                o.z = (int)f2bf(fb[r][gi][4] * av[gi][4]) | ((int)f2bf(fb[r][gi][5] * av[gi][5]) << 16);
                o.w = (int)f2bf(fb[r][gi][6] * av[gi][6]) | ((int)f2bf(fb[r][gi][7] * av[gi][7]) << 16);
                *(int4*)(xs + ((s0 + r) & 7) * 4224 + (lane + 1) * 64 + ((wv + gi * 4) * 0 + (g ^ (lane & 7)) * 8)) = o;
            }
    };

    // ---- prologue: rows yb-1..yb+2 -> slots 0..3 ----
    stage_load(yb - 1); stage_store(0);
    stage_load(yb + 1); stage_store(2);

    int si[3][2];   // per-(dx,kc) ds base; pixel-tile n folds into +n*1024 offset imm
#pragma unroll
    for (int dxi = 0; dxi < 3; ++dxi)
#pragma unroll
        for (int kc = 0; kc < 2; ++kc) {
            int wx = co_l + dxi - 1;                       // -1..15
            si[dxi][kc] = (wx + 1) * 64 + (((kc * 4 + kg) ^ (wx & 7)) * 8);
        }

    __syncthreads();

    // ---- 8-step pipelined main loop ----
    for (int it = 0; it < NSTEP; ++it) {
        // (a) issue next-2-rows loads; latency hides under MFMA
        if (it < NSTEP - 1) stage_load(yb + 2 * it + 3);

        // (b) compute this step's 2 output rows
        f32x4 acc[2][4] = {};
#pragma unroll
        for (int tap = 0; tap < 9; ++tap) {
            const int ky  = tap / 3;
            const int dxi = tap - 3 * ky;
            const short* rowp = xs + ((2 * it + rw + ky) & 7) * 4224;
#pragma unroll
            for (int kc = 0; kc < 2; ++kc) {
                const short* bp = rowp + si[dxi][kc];
#pragma unroll
                for (int n = 0; n < 4; ++n) {
                    bf16x8 bfr = *(const bf16x8*)(bp + n * 1024);   // offset imm
                    acc[0][n] = __builtin_amdgcn_mfma_f32_16x16x32_bf16(
                        wreg[0][tap][kc], bfr, acc[0][n], 0, 0, 0);
                    acc[1][n] = __builtin_amdgcn_mfma_f32_16x16x32_bf16(
                        wreg[1][tap][kc], bfr, acc[1][n], 0, 0, 0);
                }
            }
        }

        // (c) convert + ring write (vmcnt wait for (a) lands here)
        if (it < NSTEP - 1) stage_store(2 * it + 4);

        // (d) barrier, then (e) nt-stores drain under next step's work
        if (it < NSTEP - 1) __syncthreads();

        const int y = yb + 2 * it + rw;
#pragma unroll
        for (int m = 0; m < 2; ++m)
#pragma unroll
            for (int rr = 0; rr < 4; ++rr) {
                const int co = (mg * 2 + m) * 16 + kg * 4 + rr;
                const float bv = bias[co];
                float* op = out + (size_t)(((b * COUT + co) * TT + t) * HH + y) * WW;
#pragma unroll
                for (int n = 0; n < 4; ++n)
                    __builtin_nontemporal_store(acc[m][n][rr] + bv, &op[n * 16 + co_l]);
            }
    }
}

extern "C" void kernel_launch(void* const* d_in, const int* in_sizes, int n_in,
                              void* d_out, int out_size, void* d_ws, size_t ws_size,
                              hipStream_t stream) {
    const float* x      = (const float*)d_in[0];
    const float* alpha  = (const float*)d_in[1];
    const float* weight = (const float*)d_in[2];
    const float* bias   = (const float*)d_in[3];
    float* out          = (float*)d_out;

    // workspace: wb only (73.7 KB)
    unsigned short* wb = (unsigned short*)d_ws;

    hipLaunchKernelGGL(prep_w, dim3(144), dim3(256), 0, stream, weight, wb);
    hipLaunchKernelGGL(conv9, dim3(8 * 64), dim3(256), 0, stream,
                       x, alpha, (const short*)wb, bias, out);
}